// Round 13
// baseline (38.554 us; speedup 1.0000x reference)
//
#include <hip/hip_runtime.h>
#include <math.h>
#include <stdint.h>

#define D    128
#define CCLS 64
#define CH   16     // column chunks; grid = (M/128) x CH

typedef _Float16 f16x8 __attribute__((ext_vector_type(8)));
typedef float    f32x4 __attribute__((ext_vector_type(4)));

__device__ __forceinline__ float wave_reduce_sum(float v) {
    #pragma unroll
    for (int off = 32; off > 0; off >>= 1) v += __shfl_xor(v, off, 64);
    return v;
}

__device__ __forceinline__ void gload_lds16(const void* g, void* l) {
    __builtin_amdgcn_global_load_lds(
        (const __attribute__((address_space(1))) uint32_t*)g,
        (__attribute__((address_space(3))) uint32_t*)l, 16, 0, 0);
}
__device__ __forceinline__ void gload_lds4(const void* g, void* l) {
    __builtin_amdgcn_global_load_lds(
        (const __attribute__((address_space(1))) uint32_t*)g,
        (__attribute__((address_space(3))) uint32_t*)l, 4, 0, 0);
}

// --- normalize rows (feats ++ protos ++ zero-pad), fold sqrt(log2e/TAU),
//     cast f16, MFMA-tiled layout: elem(r,k) ->
//     ((r>>4)*16 + (k>>3))*128 + (r&15)*8 + (k&7).  One wave per row.
//     ALSO: block 0 does the class histogram + zeroes loss_sum/ticket;
//     ALSO: materializes labs[] = concat(t2, t3).
__global__ void norm_kernel(const float* __restrict__ protos,
                            const float* __restrict__ proj2,
                            const float* __restrict__ proj3,
                            const int* __restrict__ t2, const int* __restrict__ t3,
                            _Float16* __restrict__ ftile, int* __restrict__ labs,
                            float* __restrict__ cls_freq, float* __restrict__ loss_sum,
                            int* __restrict__ ticket, int N, int M) {
    const float SCL = 3.8017368953f;  // sqrt(10 * log2(e))
    int w = threadIdx.x >> 6;
    int lane = threadIdx.x & 63;
    int row = blockIdx.x * (blockDim.x >> 6) + w;
    const int MT = M + 128;

    if (blockIdx.x == 0) {             // fused class histogram (one block)
        __shared__ int h[CCLS];
        int t = threadIdx.x;
        if (t < CCLS) h[t] = 0;
        if (t == 0) { loss_sum[0] = 0.f; ticket[0] = 0; }
        __syncthreads();
        for (int i = t; i < M; i += blockDim.x) {
            int lab = (i < N) ? t2[i] : t3[i - N];
            atomicAdd(&h[lab], 1);
        }
        __syncthreads();
        if (t < CCLS) cls_freq[t] = (float)h[t] + 1.0f + 1e-6f;
    }

    if (row < MT) {
        const float* src = nullptr;
        if (row < M)             src = (row < N) ? proj2 + (size_t)row * D
                                                 : proj3 + (size_t)(row - N) * D;
        else if (row < M + CCLS) src = protos + (size_t)(row - M) * D;
        float2 v = {0.f, 0.f};
        if (src) v = ((const float2*)src)[lane];
        float ss = wave_reduce_sum(v.x * v.x + v.y * v.y);
        float scale = src ? SCL / fmaxf(sqrtf(ss), 1e-12f) : 0.f;
        _Float16 h0 = (_Float16)(v.x * scale), h1 = (_Float16)(v.y * scale);
        int k0 = 2 * lane;
        size_t off = ((size_t)(row >> 4) * 16 + (k0 >> 3)) * 128 + (row & 15) * 8 + (k0 & 7);
        ftile[off] = h0; ftile[off + 1] = h1;
        if (row < M && lane == 0)
            labs[row] = (row < N) ? t2[row] : t3[row - N];
    }
}

// --- main: 128-row panel per block.x, 8-slice chunk per block.y.
//     4 waves x 32 rows (256 threads). Slice body is N-OUTER: per column
//     sub-tile n: {4 ds_read_b128 -> 8 MFMA -> epilogue(n)} so the exp2/VALU
//     epilogue of sub-tile n overlaps the MFMAs of n+1 inside the wave
//     (R12's [all-MFMA][all-epilogue] phases serialized the pipes).
//     Swapped MFMA keeps row lane-local: rd/rn are per-lane scalars.
__global__ __launch_bounds__(256, 4)
void sim_kernel(const _Float16* __restrict__ ftile,
                const int* __restrict__ labs,
                const float* __restrict__ cls_freq,
                float* __restrict__ nPart, float* __restrict__ dPart,
                float* __restrict__ rp, int M) {
    __shared__ _Float16 sbuf[2][8320];   // per buf: 16KB B-tile + 256B labels

    const int panel = blockIdx.x;         // [0, M/128)
    const int chunk = blockIdx.y;         // [0, CH)
    const int t = threadIdx.x;
    const int w = t >> 6, lane = t & 63;  // w in [0,4)
    const int g = lane >> 4, li = lane & 15;
    const int lo = g * 128 + li * 8;
    const int rtA = panel * 8 + w * 2;    // wave's two 16-row A tiles
    const int nS = (M / 64) / CH;         // 8 slices per chunk
    const int sBase = chunk * nS;
    const int row0 = panel * 128 + 32 * w + li;   // lane's two rows: row0, row0+16
    const int rl0 = labs[row0];
    const int rl1 = labs[row0 + 16];

    // A fragments: this wave's 32 rows x 128 k
    f16x8 a[2][4];
    #pragma unroll
    for (int m = 0; m < 2; ++m)
        #pragma unroll
        for (int kt = 0; kt < 4; ++kt)
            a[m][kt] = *(const f16x8*)(ftile + (size_t)(rtA + m) * 2048 + kt * 512 + lo);

    float rn[2] = {0.f, 0.f}, rd[2] = {0.f, 0.f};
    float rpacc[2] = {0.f, 0.f};

    // ---- staging: 16 x 1KB B issues (4 per wave) + 256B labels (wave 0)
    #define STAGE(buf, s)                                                        \
        {                                                                        \
            const char* bsrc_ = (const char*)ftile + (size_t)(s) * 16384;        \
            char* dst_ = (char*)&sbuf[(buf)][0];                                 \
            _Pragma("unroll")                                                    \
            for (int q = 0; q < 4; ++q) {                                        \
                int j_ = w * 4 + q;                                              \
                gload_lds16(bsrc_ + (size_t)j_ * 1024 + lane * 16,               \
                            dst_ + (size_t)j_ * 1024);                           \
            }                                                                    \
            if (w == 0)                                                          \
                gload_lds4((const char*)labs + (size_t)(s) * 256 + lane * 4,     \
                           dst_ + 16384);                                        \
        }

    STAGE(0, sBase);
    __syncthreads();                       // compiler drains vmcnt before barrier
    int cur = 0;

    const int diagS = 2 * panel + (w >> 1);   // slice containing this wave's rows
    const int nD0 = 2 * (w & 1);              // diag n-index for m: n == nD0 + m

    for (int si = 0; si < nS; ++si) {
        const int s = sBase + si;
        if (si + 1 < nS) STAGE(cur ^ 1, sBase + si + 1);

        const _Float16* Bl = &sbuf[cur][0];
        const int* clabL = (const int*)&sbuf[cur][8192];
        const bool isDiag = (s == diagS);

        #pragma unroll
        for (int n = 0; n < 4; ++n) {
            f16x8 bn[4];
            #pragma unroll
            for (int kt = 0; kt < 4; ++kt)
                bn[kt] = *(const f16x8*)(Bl + n * 2048 + kt * 512 + lo);

            f32x4 acc[2];
            #pragma unroll
            for (int m = 0; m < 2; ++m)
                #pragma unroll
                for (int r = 0; r < 4; ++r) acc[m][r] = 0.f;

            #pragma unroll
            for (int kt = 0; kt < 4; ++kt)
                #pragma unroll
                for (int m = 0; m < 2; ++m)
                    acc[m] = __builtin_amdgcn_mfma_f32_16x16x32_f16(bn[kt], a[m][kt], acc[m], 0, 0, 0);

            // diagonal mask: static indices, runtime predicate (v_cndmask)
            if (isDiag) {
                #pragma unroll
                for (int m = 0; m < 2; ++m)
                    #pragma unroll
                    for (int r = 0; r < 4; ++r)
                        acc[m][r] = (n == nD0 + m && 4 * g + r == li) ? -1e5f : acc[m][r];
            }

            // epilogue(n): e = exp2(P); rd += e; rn += match ? e : 0
            int4 c4 = *(const int4*)(clabL + 16 * n + 4 * g);
            #pragma unroll
            for (int m = 0; m < 2; ++m) {
                float e0 = __builtin_amdgcn_exp2f(acc[m][0]);
                float e1 = __builtin_amdgcn_exp2f(acc[m][1]);
                float e2 = __builtin_amdgcn_exp2f(acc[m][2]);
                float e3 = __builtin_amdgcn_exp2f(acc[m][3]);
                const int rl = m ? rl1 : rl0;
                rd[m] += e0 + e1 + e2 + e3;
                rn[m] += (c4.x == rl) ? e0 : 0.f;
                rn[m] += (c4.y == rl) ? e1 : 0.f;
                rn[m] += (c4.z == rl) ? e2 : 0.f;
                rn[m] += (c4.w == rl) ? e3 : 0.f;
            }
        }

        __syncthreads();                   // drains stage loads + LDS reads
        cur ^= 1;
    }

    // proto slice (chunk 0 only): rp = sum_c e/freq_c; numer += e[lab]
    if (chunk == 0) {
        const int rbp = M >> 4;
        #pragma unroll
        for (int n = 0; n < 4; ++n) {
            f16x8 bn[4];
            #pragma unroll
            for (int kt = 0; kt < 4; ++kt)
                bn[kt] = *(const f16x8*)(ftile + (size_t)(rbp + n) * 2048 + kt * 512 + lo);
            f32x4 acc[2];
            #pragma unroll
            for (int m = 0; m < 2; ++m)
                #pragma unroll
                for (int r = 0; r < 4; ++r) acc[m][r] = 0.f;
            #pragma unroll
            for (int kt = 0; kt < 4; ++kt)
                #pragma unroll
                for (int m = 0; m < 2; ++m)
                    acc[m] = __builtin_amdgcn_mfma_f32_16x16x32_f16(bn[kt], a[m][kt], acc[m], 0, 0, 0);

            f32x4 fr = *(const f32x4*)(cls_freq + 16 * n + 4 * g);
            const int c0 = 16 * n + 4 * g;
            #pragma unroll
            for (int m = 0; m < 2; ++m) {
                float e0 = __builtin_amdgcn_exp2f(acc[m][0]);
                float e1 = __builtin_amdgcn_exp2f(acc[m][1]);
                float e2 = __builtin_amdgcn_exp2f(acc[m][2]);
                float e3 = __builtin_amdgcn_exp2f(acc[m][3]);
                const int rl = m ? rl1 : rl0;
                rpacc[m] += e0 / fr[0] + e1 / fr[1] + e2 / fr[2] + e3 / fr[3];
                rn[m] += (c0 + 0 == rl) ? e0 : 0.f;
                rn[m] += (c0 + 1 == rl) ? e1 : 0.f;
                rn[m] += (c0 + 2 == rl) ? e2 : 0.f;
                rn[m] += (c0 + 3 == rl) ? e3 : 0.f;
            }
        }
    }

    // reduce over the 4 lane-groups (same rows), then coalesced stores
    #pragma unroll
    for (int m = 0; m < 2; ++m) {
        rn[m] += __shfl_xor(rn[m], 16, 64); rn[m] += __shfl_xor(rn[m], 32, 64);
        rd[m] += __shfl_xor(rd[m], 16, 64); rd[m] += __shfl_xor(rd[m], 32, 64);
        if (chunk == 0) {
            rpacc[m] += __shfl_xor(rpacc[m], 16, 64);
            rpacc[m] += __shfl_xor(rpacc[m], 32, 64);
        }
    }
    if (lane < 16) {
        #pragma unroll
        for (int m = 0; m < 2; ++m) {
            const int rowm = row0 + 16 * m;
            nPart[(size_t)chunk * M + rowm] = rn[m];
            dPart[(size_t)chunk * M + rowm] = rd[m];
            if (chunk == 0) rp[rowm] = rpacc[m];
        }
    }
}

// --- per-row loss + mean accumulate; last block (ticket) writes the output --
__global__ void fin_kernel(const int* __restrict__ labs,
                           const float* __restrict__ cls_freq,
                           const float* __restrict__ nPart,
                           const float* __restrict__ dPart,
                           const float* __restrict__ rp,
                           float* __restrict__ loss_sum, int* __restrict__ ticket,
                           float* __restrict__ out, int M) {
    int i = blockIdx.x * blockDim.x + threadIdx.x;
    float l = 0.f;
    if (i < M) {
        float rnT = 0.f, rdT = 0.f;
        #pragma unroll
        for (int ch = 0; ch < CH; ++ch) {
            rnT += nPart[(size_t)ch * M + i];
            rdT += dPart[(size_t)ch * M + i];
        }
        float denom = rdT / cls_freq[labs[i]] + rp[i];
        l = logf(denom + 1e-12f) - logf(rnT);
    }
    l = wave_reduce_sum(l);
    __shared__ float ws_[4];
    if ((threadIdx.x & 63) == 0) ws_[threadIdx.x >> 6] = l;
    __syncthreads();
    if (threadIdx.x == 0) {
        atomicAdd(loss_sum, ws_[0] + ws_[1] + ws_[2] + ws_[3]);
        __threadfence();
        int old = atomicAdd(ticket, 1);
        if (old == (int)gridDim.x - 1) {
            __threadfence();
            out[0] = *(volatile float*)loss_sum / (float)M;
        }
    }
}

extern "C" void kernel_launch(void* const* d_in, const int* in_sizes, int n_in,
                              void* d_out, int out_size, void* d_ws, size_t ws_size,
                              hipStream_t stream) {
    const float* protos = (const float*)d_in[0];
    const float* proj2  = (const float*)d_in[1];
    const int*   t2     = (const int*)d_in[2];
    const float* proj3  = (const float*)d_in[3];
    const int*   t3     = (const int*)d_in[4];
    float* out = (float*)d_out;

    const int N = in_sizes[1] / D;   // 4096
    const int M = 2 * N;             // 8192
    const int MT = M + 128;

    _Float16* ftile = (_Float16*)d_ws;                 // MT*D halfs (1KB-tiled)
    int*   labs     = (int*)(ftile + (size_t)MT * D);  // M ints
    float* cls_freq = (float*)(labs + M);              // 64
    float* nPart    = cls_freq + CCLS;                 // CH*M
    float* dPart    = nPart + (size_t)CH * M;          // CH*M
    float* rp       = dPart + (size_t)CH * M;          // M
    float* loss_sum = rp + M;                          // 1
    int*   ticket   = (int*)(loss_sum + 1);            // 1

    norm_kernel<<<(MT + 3) / 4, 256, 0, stream>>>(protos, proj2, proj3, t2, t3,
                                                  ftile, labs, cls_freq, loss_sum,
                                                  ticket, N, M);
    dim3 grid(M / 128, CH);
    sim_kernel<<<grid, 256, 0, stream>>>(ftile, labs, cls_freq, nPart, dPart, rp, M);
    fin_kernel<<<(M + 255) / 256, 256, 0, stream>>>(labs, cls_freq, nPart, dPart, rp,
                                                    loss_sum, ticket, out, M);
}

// Round 14
// 37.520 us; speedup vs baseline: 1.0275x; 1.0275x over previous
//
#include <hip/hip_runtime.h>
#include <math.h>
#include <stdint.h>

#define D    128
#define CCLS 64
#define CH   16     // column chunks; grid = (M/128) x CH
#define HB   8      // histogram partial blocks

typedef _Float16 f16x8 __attribute__((ext_vector_type(8)));
typedef float    f32x4 __attribute__((ext_vector_type(4)));

__device__ __forceinline__ float wave_reduce_sum(float v) {
    #pragma unroll
    for (int off = 32; off > 0; off >>= 1) v += __shfl_xor(v, off, 64);
    return v;
}

__device__ __forceinline__ void gload_lds16(const void* g, void* l) {
    __builtin_amdgcn_global_load_lds(
        (const __attribute__((address_space(1))) uint32_t*)g,
        (__attribute__((address_space(3))) uint32_t*)l, 16, 0, 0);
}
__device__ __forceinline__ void gload_lds4(const void* g, void* l) {
    __builtin_amdgcn_global_load_lds(
        (const __attribute__((address_space(1))) uint32_t*)g,
        (__attribute__((address_space(3))) uint32_t*)l, 4, 0, 0);
}

// --- normalize rows (feats ++ protos ++ zero-pad), fold sqrt(log2e/TAU),
//     cast f16, MFMA-tiled layout. One wave per row.
//     Histogram SPREAD over blocks 0..7 (partials, no serial straggler);
//     block 8 zeroes loss_sum/ticket; labs[] materialized.
__global__ void norm_kernel(const float* __restrict__ protos,
                            const float* __restrict__ proj2,
                            const float* __restrict__ proj3,
                            const int* __restrict__ t2, const int* __restrict__ t3,
                            _Float16* __restrict__ ftile, int* __restrict__ labs,
                            float* __restrict__ hpart, float* __restrict__ loss_sum,
                            int* __restrict__ ticket, int N, int M) {
    const float SCL = 3.8017368953f;  // sqrt(10 * log2(e))
    int w = threadIdx.x >> 6;
    int lane = threadIdx.x & 63;
    int row = blockIdx.x * (blockDim.x >> 6) + w;
    const int MT = M + 128;

    if (blockIdx.x < HB) {             // partial class histogram
        __shared__ int h[CCLS];
        int t = threadIdx.x;
        if (t < CCLS) h[t] = 0;
        __syncthreads();
        int base = blockIdx.x * (M / HB);
        for (int i = t; i < M / HB; i += (int)blockDim.x) {
            int gi = base + i;
            int lab = (gi < N) ? t2[gi] : t3[gi - N];
            atomicAdd(&h[lab], 1);
        }
        __syncthreads();
        if (t < CCLS) hpart[blockIdx.x * CCLS + t] = (float)h[t];
    }
    if (blockIdx.x == HB && threadIdx.x == 0) { loss_sum[0] = 0.f; ticket[0] = 0; }

    if (row < MT) {
        const float* src = nullptr;
        if (row < M)             src = (row < N) ? proj2 + (size_t)row * D
                                                 : proj3 + (size_t)(row - N) * D;
        else if (row < M + CCLS) src = protos + (size_t)(row - M) * D;
        float2 v = {0.f, 0.f};
        if (src) v = ((const float2*)src)[lane];
        float ss = wave_reduce_sum(v.x * v.x + v.y * v.y);
        float scale = src ? SCL / fmaxf(sqrtf(ss), 1e-12f) : 0.f;
        _Float16 h0 = (_Float16)(v.x * scale), h1 = (_Float16)(v.y * scale);
        int k0 = 2 * lane;
        size_t off = ((size_t)(row >> 4) * 16 + (k0 >> 3)) * 128 + (row & 15) * 8 + (k0 & 7);
        ftile[off] = h0; ftile[off + 1] = h1;
        if (row < M && lane == 0)
            labs[row] = (row < N) ? t2[row] : t3[row - N];
    }
}

// --- main: 128-row panel x 8-slice chunk per block; 4 waves x 32 rows.
//     T4-lite pipeline: 16 half-slices (32 cols, 8KB), THREE LDS buffers,
//     raw s_barrier + counted s_waitcnt vmcnt(2) -- prefetch stays 2 deep
//     across barriers (never drained to 0 in the loop; __syncthreads would
//     emit vmcnt(0) and expose full L2 latency every slice -- the invariant
//     cost R12/R13 couldn't move). Read buf[h%3], write buf[(h+2)%3]:
//     disjoint under per-h barrier lockstep. Labels for the whole chunk
//     staged once in the prologue (oldest loads, covered by first wait).
__global__ __launch_bounds__(256, 4)
void sim_kernel(const _Float16* __restrict__ ftile,
                const int* __restrict__ labs,
                const float* __restrict__ hpart,
                float* __restrict__ nPart, float* __restrict__ dPart,
                float* __restrict__ rp, int M) {
    __shared__ _Float16 bbuf[3][4096];    // 3 x 8KB half-slice B buffers
    __shared__ int labL[512];             // chunk's 512 column labels

    const int panel = blockIdx.x;         // [0, M/128)
    const int chunk = blockIdx.y;         // [0, CH)
    const int t = threadIdx.x;
    const int w = t >> 6, lane = t & 63;  // w in [0,4)
    const int g = lane >> 4, li = lane & 15;
    const int lo = g * 128 + li * 8;
    const int rtA = panel * 8 + w * 2;
    const int nH = 16;                    // half-slices per chunk
    const int sBase = chunk * 8;          // first slice of chunk
    const int row0 = panel * 128 + 32 * w + li;
    const int rl0 = labs[row0];
    const int rl1 = labs[row0 + 16];

    // A fragments: this wave's 32 rows x 128 k
    f16x8 a[2][4];
    #pragma unroll
    for (int m = 0; m < 2; ++m)
        #pragma unroll
        for (int kt = 0; kt < 4; ++kt)
            a[m][kt] = *(const f16x8*)(ftile + (size_t)(rtA + m) * 2048 + kt * 512 + lo);

    float rn[2] = {0.f, 0.f}, rd[2] = {0.f, 0.f};

    // prologue: labels first (oldest), then half-stages 0 and 1
    {
        const char* lsrc = (const char*)labs + (size_t)sBase * 256;
        #pragma unroll
        for (int c = 0; c < 2; ++c) {
            int cc = w * 2 + c;
            gload_lds4(lsrc + cc * 256 + lane * 4, (char*)labL + cc * 256);
        }
    }
    #define STAGE_H(buf, h)                                                       \
        {                                                                         \
            const char* src_ = (const char*)ftile + (size_t)sBase * 16384         \
                               + (size_t)(h) * 8192;                              \
            char* dst_ = (char*)&bbuf[(buf)][0];                                  \
            _Pragma("unroll")                                                     \
            for (int c = 0; c < 2; ++c) {                                         \
                int j_ = w * 2 + c;                                               \
                gload_lds16(src_ + (size_t)j_ * 1024 + lane * 16,                 \
                            dst_ + (size_t)j_ * 1024);                            \
            }                                                                     \
        }
    STAGE_H(0, 0);
    STAGE_H(1, 1);

    const int diagS = 2 * panel + (w >> 1);   // slice containing this wave's rows
    const int nD0 = 2 * (w & 1);              // diag n (within slice) = nD0 + m

    for (int h = 0; h < nH; ++h) {
        // counted wait: stage h complete, stage h+1 (2 issues) stays in flight
        if (h < nH - 1) { asm volatile("s_waitcnt vmcnt(2)" ::: "memory"); }
        else            { asm volatile("s_waitcnt vmcnt(0)" ::: "memory"); }
        __builtin_amdgcn_s_barrier();

        const _Float16* Bl = &bbuf[h % 3][0];
        const int s = sBase + (h >> 1);
        const bool isDiag = (s == diagS);
        const int nBase = (h & 1) * 2;        // absolute n within slice

        #pragma unroll
        for (int nl = 0; nl < 2; ++nl) {
            f16x8 bn[4];
            #pragma unroll
            for (int kt = 0; kt < 4; ++kt)
                bn[kt] = *(const f16x8*)(Bl + nl * 2048 + kt * 512 + lo);

            f32x4 acc[2];
            #pragma unroll
            for (int m = 0; m < 2; ++m)
                #pragma unroll
                for (int r = 0; r < 4; ++r) acc[m][r] = 0.f;

            #pragma unroll
            for (int kt = 0; kt < 4; ++kt)
                #pragma unroll
                for (int m = 0; m < 2; ++m)
                    acc[m] = __builtin_amdgcn_mfma_f32_16x16x32_f16(bn[kt], a[m][kt], acc[m], 0, 0, 0);

            if (isDiag) {
                #pragma unroll
                for (int m = 0; m < 2; ++m)
                    #pragma unroll
                    for (int r = 0; r < 4; ++r)
                        acc[m][r] = (nBase + nl == nD0 + m && 4 * g + r == li)
                                    ? -1e5f : acc[m][r];
            }

            int4 c4 = *(const int4*)(labL + h * 32 + nl * 16 + 4 * g);
            #pragma unroll
            for (int m = 0; m < 2; ++m) {
                float e0 = __builtin_amdgcn_exp2f(acc[m][0]);
                float e1 = __builtin_amdgcn_exp2f(acc[m][1]);
                float e2 = __builtin_amdgcn_exp2f(acc[m][2]);
                float e3 = __builtin_amdgcn_exp2f(acc[m][3]);
                const int rl = m ? rl1 : rl0;
                rd[m] += e0 + e1 + e2 + e3;
                rn[m] += (c4.x == rl) ? e0 : 0.f;
                rn[m] += (c4.y == rl) ? e1 : 0.f;
                rn[m] += (c4.z == rl) ? e2 : 0.f;
                rn[m] += (c4.w == rl) ? e3 : 0.f;
            }
        }

        if (h + 2 < nH) STAGE_H((h + 2) % 3, h + 2);
    }

    // proto slice (chunk 0 only): rp = sum_c e/freq_c; numer += e[lab];
    // class freqs re-summed from the 8 histogram partials.
    float rpacc[2] = {0.f, 0.f};
    if (chunk == 0) {
        const int rbp = M >> 4;
        #pragma unroll
        for (int n = 0; n < 4; ++n) {
            f16x8 bn[4];
            #pragma unroll
            for (int kt = 0; kt < 4; ++kt)
                bn[kt] = *(const f16x8*)(ftile + (size_t)(rbp + n) * 2048 + kt * 512 + lo);
            f32x4 acc[2];
            #pragma unroll
            for (int m = 0; m < 2; ++m)
                #pragma unroll
                for (int r = 0; r < 4; ++r) acc[m][r] = 0.f;
            #pragma unroll
            for (int kt = 0; kt < 4; ++kt)
                #pragma unroll
                for (int m = 0; m < 2; ++m)
                    acc[m] = __builtin_amdgcn_mfma_f32_16x16x32_f16(bn[kt], a[m][kt], acc[m], 0, 0, 0);

            f32x4 fr = {1.0f + 1e-6f, 1.0f + 1e-6f, 1.0f + 1e-6f, 1.0f + 1e-6f};
            #pragma unroll
            for (int b = 0; b < HB; ++b)
                fr += *(const f32x4*)(hpart + b * CCLS + 16 * n + 4 * g);
            const int c0 = 16 * n + 4 * g;
            #pragma unroll
            for (int m = 0; m < 2; ++m) {
                float e0 = __builtin_amdgcn_exp2f(acc[m][0]);
                float e1 = __builtin_amdgcn_exp2f(acc[m][1]);
                float e2 = __builtin_amdgcn_exp2f(acc[m][2]);
                float e3 = __builtin_amdgcn_exp2f(acc[m][3]);
                const int rl = m ? rl1 : rl0;
                rpacc[m] += e0 / fr[0] + e1 / fr[1] + e2 / fr[2] + e3 / fr[3];
                rn[m] += (c0 + 0 == rl) ? e0 : 0.f;
                rn[m] += (c0 + 1 == rl) ? e1 : 0.f;
                rn[m] += (c0 + 2 == rl) ? e2 : 0.f;
                rn[m] += (c0 + 3 == rl) ? e3 : 0.f;
            }
        }
    }

    // reduce over the 4 lane-groups (same rows), then coalesced stores
    #pragma unroll
    for (int m = 0; m < 2; ++m) {
        rn[m] += __shfl_xor(rn[m], 16, 64); rn[m] += __shfl_xor(rn[m], 32, 64);
        rd[m] += __shfl_xor(rd[m], 16, 64); rd[m] += __shfl_xor(rd[m], 32, 64);
        if (chunk == 0) {
            rpacc[m] += __shfl_xor(rpacc[m], 16, 64);
            rpacc[m] += __shfl_xor(rpacc[m], 32, 64);
        }
    }
    if (lane < 16) {
        #pragma unroll
        for (int m = 0; m < 2; ++m) {
            const int rowm = row0 + 16 * m;
            nPart[(size_t)chunk * M + rowm] = rn[m];
            dPart[(size_t)chunk * M + rowm] = rd[m];
            if (chunk == 0) rp[rowm] = rpacc[m];
        }
    }
}

// --- per-row loss + mean accumulate; last block (ticket) writes output ------
__global__ void fin_kernel(const int* __restrict__ labs,
                           const float* __restrict__ hpart,
                           const float* __restrict__ nPart,
                           const float* __restrict__ dPart,
                           const float* __restrict__ rp,
                           float* __restrict__ loss_sum, int* __restrict__ ticket,
                           float* __restrict__ out, int M) {
    int i = blockIdx.x * blockDim.x + threadIdx.x;
    float l = 0.f;
    if (i < M) {
        float rnT = 0.f, rdT = 0.f;
        #pragma unroll
        for (int ch = 0; ch < CH; ++ch) {
            rnT += nPart[(size_t)ch * M + i];
            rdT += dPart[(size_t)ch * M + i];
        }
        int lab = labs[i];
        float fsum = 1.0f + 1e-6f;
        #pragma unroll
        for (int b = 0; b < HB; ++b) fsum += hpart[b * CCLS + lab];
        float denom = rdT / fsum + rp[i];
        l = logf(denom + 1e-12f) - logf(rnT);
    }
    l = wave_reduce_sum(l);
    __shared__ float ws_[4];
    if ((threadIdx.x & 63) == 0) ws_[threadIdx.x >> 6] = l;
    __syncthreads();
    if (threadIdx.x == 0) {
        atomicAdd(loss_sum, ws_[0] + ws_[1] + ws_[2] + ws_[3]);
        __threadfence();
        int old = atomicAdd(ticket, 1);
        if (old == (int)gridDim.x - 1) {
            __threadfence();
            out[0] = *(volatile float*)loss_sum / (float)M;
        }
    }
}

extern "C" void kernel_launch(void* const* d_in, const int* in_sizes, int n_in,
                              void* d_out, int out_size, void* d_ws, size_t ws_size,
                              hipStream_t stream) {
    const float* protos = (const float*)d_in[0];
    const float* proj2  = (const float*)d_in[1];
    const int*   t2     = (const int*)d_in[2];
    const float* proj3  = (const float*)d_in[3];
    const int*   t3     = (const int*)d_in[4];
    float* out = (float*)d_out;

    const int N = in_sizes[1] / D;   // 4096
    const int M = 2 * N;             // 8192
    const int MT = M + 128;

    _Float16* ftile = (_Float16*)d_ws;                 // MT*D halfs (1KB-tiled)
    int*   labs     = (int*)(ftile + (size_t)MT * D);  // M ints
    float* hpart    = (float*)(labs + M);              // HB*CCLS
    float* nPart    = hpart + HB * CCLS;               // CH*M
    float* dPart    = nPart + (size_t)CH * M;          // CH*M
    float* rp       = dPart + (size_t)CH * M;          // M
    float* loss_sum = rp + M;                          // 1
    int*   ticket   = (int*)(loss_sum + 1);            // 1

    norm_kernel<<<(MT + 3) / 4, 256, 0, stream>>>(protos, proj2, proj3, t2, t3,
                                                  ftile, labs, hpart, loss_sum,
                                                  ticket, N, M);
    dim3 grid(M / 128, CH);
    sim_kernel<<<grid, 256, 0, stream>>>(ftile, labs, hpart, nPart, dPart, rp, M);
    fin_kernel<<<(M + 255) / 256, 256, 0, stream>>>(labs, hpart, nPart, dPart, rp,
                                                    loss_sum, ticket, out, M);
}